// Round 1
// baseline (75.933 us; speedup 1.0000x reference)
//
#include <hip/hip_runtime.h>
#include <hip/hip_bf16.h>

#define KK 32
#define DD 512
#define BB 16
#define NN 4096

typedef __attribute__((ext_vector_type(8))) short short8;
typedef __attribute__((ext_vector_type(4))) float f32x4;

__device__ __forceinline__ unsigned short f2bf(float f) {
    unsigned u = __builtin_bit_cast(unsigned, f);
    u += 0x7fffu + ((u >> 16) & 1u);   // round-to-nearest-even bf16
    return (unsigned short)(u >> 16);
}

// ---------------- kernel 0: c2[k], s2[k], zero sA ----------------
__global__ __launch_bounds__(256) void k_prep(const float* __restrict__ codes,
                                              const float* __restrict__ scale,
                                              float* __restrict__ sA,
                                              float* __restrict__ c2w,
                                              float* __restrict__ s2w) {
    __shared__ float red[KK][8];
    int tid = threadIdx.x;
    int k = tid >> 3, part = tid & 7;
    const float4* p = reinterpret_cast<const float4*>(codes + k * DD + part * 64);
    float s = 0.f;
#pragma unroll
    for (int i = 0; i < 16; ++i) {
        float4 v = p[i];
        s += v.x * v.x + v.y * v.y + v.z * v.z + v.w * v.w;
    }
    red[k][part] = s;
    sA[tid] = 0.f;
    sA[tid + 256] = 0.f;
    __syncthreads();
    if (tid < KK) {
        float c2 = 0.f;
#pragma unroll
        for (int j = 0; j < 8; ++j) c2 += red[tid][j];
        c2w[tid] = c2;
        float sc = scale[tid];
        s2w[tid] = sc * sc;
    }
}

// ---------------- kernel 1: softmax assignments A[b,n,k] ----------------
// block = 256 threads (4 waves), 128 tokens/block, grid = 16*32 = 512
__global__ __launch_bounds__(256) void k_assign(const float* __restrict__ x,
                                                const float* __restrict__ codes,
                                                const float* __restrict__ c2w,
                                                const float* __restrict__ s2w,
                                                float* __restrict__ Aout,
                                                float* __restrict__ sA) {
    __shared__ unsigned short codes_lds[KK][DD + 8];   // bf16, padded row
    int tid = threadIdx.x;
    int bid = blockIdx.x;
    int b = bid >> 5;                 // 32 blocks per batch
    int tok_base = (bid & 31) << 7;   // *128

    // stage codes -> LDS as bf16
#pragma unroll
    for (int i = 0; i < 16; ++i) {
        int idx = i * 1024 + tid * 4;
        int k = idx >> 9, d = idx & 511;
        float4 v = *reinterpret_cast<const float4*>(codes + idx);
        ushort4 h;
        h.x = f2bf(v.x); h.y = f2bf(v.y); h.z = f2bf(v.z); h.w = f2bf(v.w);
        *reinterpret_cast<ushort4*>(&codes_lds[k][d]) = h;
    }
    __syncthreads();

    int lane = tid & 63;
    int w = tid >> 6;              // wave 0..3 -> 32 tokens each
    int g = lane >> 4, c = lane & 15;
    int t0 = tok_base + w * 32;

    float s2k[2], c2k[2];
#pragma unroll
    for (int kt = 0; kt < 2; ++kt) {
        s2k[kt] = s2w[c + 16 * kt];
        c2k[kt] = c2w[c + 16 * kt];
    }

    f32x4 acc[2][2] = {};          // [token-tile][k-tile]
    float x2p[2] = {0.f, 0.f};
    const size_t rowbase = (size_t)b * DD * NN;

    for (int d0 = 0; d0 < DD; d0 += 32) {
        short8 af[2];
#pragma unroll
        for (int tt = 0; tt < 2; ++tt) {
            // A-frag: row = token (lane&15), kdim = d (g*8+j) -> transposed gather
            const float* px = x + rowbase + (size_t)(d0 + g * 8) * NN + (t0 + tt * 16 + c);
            float xv[8];
#pragma unroll
            for (int j = 0; j < 8; ++j) xv[j] = px[j * NN];
#pragma unroll
            for (int j = 0; j < 8; ++j) {
                x2p[tt] += xv[j] * xv[j];
                af[tt][j] = (short)f2bf(xv[j]);
            }
        }
        short8 bfrag[2];
#pragma unroll
        for (int kt = 0; kt < 2; ++kt)
            bfrag[kt] = *reinterpret_cast<const short8*>(&codes_lds[c + kt * 16][d0 + g * 8]);
#pragma unroll
        for (int tt = 0; tt < 2; ++tt)
#pragma unroll
            for (int kt = 0; kt < 2; ++kt)
                acc[tt][kt] = __builtin_amdgcn_mfma_f32_16x16x32_bf16(af[tt], bfrag[kt],
                                                                      acc[tt][kt], 0, 0, 0);
    }

    // complete x2 per token (lane column c): sum over the 4 g-groups
#pragma unroll
    for (int tt = 0; tt < 2; ++tt) {
        x2p[tt] += __shfl_xor(x2p[tt], 16);
        x2p[tt] += __shfl_xor(x2p[tt], 32);
    }

    float pA0 = 0.f, pA1 = 0.f;
#pragma unroll
    for (int tt = 0; tt < 2; ++tt) {
#pragma unroll
        for (int r = 0; r < 4; ++r) {
            // this thread's output row = token t0 + tt*16 + 4g + r; its x2 lives at lane 4g+r
            float x2r = __shfl(x2p[tt], g * 4 + r);
            float d0v = s2k[0] * (x2r - 2.f * acc[tt][0][r] + c2k[0]);
            float d1v = s2k[1] * (x2r - 2.f * acc[tt][1][r] + c2k[1]);
            float m = fmaxf(d0v, d1v);
            m = fmaxf(m, __shfl_xor(m, 1));
            m = fmaxf(m, __shfl_xor(m, 2));
            m = fmaxf(m, __shfl_xor(m, 4));
            m = fmaxf(m, __shfl_xor(m, 8));
            float p0 = __expf(d0v - m), p1 = __expf(d1v - m);
            float s = p0 + p1;
            s += __shfl_xor(s, 1);
            s += __shfl_xor(s, 2);
            s += __shfl_xor(s, 4);
            s += __shfl_xor(s, 8);
            float inv = 1.0f / s;
            float a0 = p0 * inv, a1 = p1 * inv;
            int tok = t0 + tt * 16 + g * 4 + r;
            float* pa = Aout + ((size_t)b * NN + tok) * KK + c;
            pa[0] = a0;
            pa[16] = a1;
            pA0 += a0;
            pA1 += a1;
        }
    }
    // block-partial column sums of a -> sA[b,k]
    pA0 += __shfl_xor(pA0, 16); pA0 += __shfl_xor(pA0, 32);
    pA1 += __shfl_xor(pA1, 16); pA1 += __shfl_xor(pA1, 32);
    if (g == 0) {
        atomicAdd(&sA[b * KK + c], pA0);
        atomicAdd(&sA[b * KK + c + 16], pA1);
    }
}

// ---------------- kernel 2: e[b,k,d] = sum_n a[n,k] x[d,n] - sA[b,k]*codes[k,d] ----------------
// block = 512 threads (8 waves), wave owns 64 d-cols, grid = 16 b * 16 n-chunks = 256
__global__ __launch_bounds__(512) void k_agg(const float* __restrict__ x,
                                             const float* __restrict__ codes,
                                             const float* __restrict__ Ain,
                                             const float* __restrict__ sA,
                                             float* __restrict__ out) {
    int tid = threadIdx.x;
    int lane = tid & 63;
    int w = tid >> 6;            // 0..7
    int g = lane >> 4, c = lane & 15;
    int bid = blockIdx.x;
    int b = bid >> 4;
    int ns = bid & 15;
    int nb = ns << 8;            // 256-token chunk

    f32x4 acc[2][4] = {};        // [k-tile][d-tile]
    const float* xb = x + (size_t)b * DD * NN;
    const float* Ab = Ain + (size_t)b * NN * KK;

    for (int nn = 0; nn < 256; nn += 32) {
        int n0 = nb + nn + g * 8;
        // A-frag: row = k (lane&15), kdim = n
        short8 af[2];
        const float* pa = Ab + (size_t)n0 * KK + c;
#pragma unroll
        for (int kt = 0; kt < 2; ++kt) {
#pragma unroll
            for (int j = 0; j < 8; ++j)
                af[kt][j] = (short)f2bf(pa[j * KK + kt * 16]);
        }
        // B-frag: col = d (lane&15), kdim = n -> x's native layout, contiguous loads
        short8 bfrag[4];
#pragma unroll
        for (int dt = 0; dt < 4; ++dt) {
            const float* px = xb + (size_t)(w * 64 + dt * 16 + c) * NN + n0;
            float4 v0 = *reinterpret_cast<const float4*>(px);
            float4 v1 = *reinterpret_cast<const float4*>(px + 4);
            short8 t;
            t[0] = (short)f2bf(v0.x); t[1] = (short)f2bf(v0.y);
            t[2] = (short)f2bf(v0.z); t[3] = (short)f2bf(v0.w);
            t[4] = (short)f2bf(v1.x); t[5] = (short)f2bf(v1.y);
            t[6] = (short)f2bf(v1.z); t[7] = (short)f2bf(v1.w);
            bfrag[dt] = t;
        }
#pragma unroll
        for (int kt = 0; kt < 2; ++kt)
#pragma unroll
            for (int dt = 0; dt < 4; ++dt)
                acc[kt][dt] = __builtin_amdgcn_mfma_f32_16x16x32_bf16(af[kt], bfrag[dt],
                                                                      acc[kt][dt], 0, 0, 0);
    }

#pragma unroll
    for (int kt = 0; kt < 2; ++kt) {
#pragma unroll
        for (int dt = 0; dt < 4; ++dt) {
            int d = w * 64 + dt * 16 + c;
#pragma unroll
            for (int r = 0; r < 4; ++r) {
                int k = kt * 16 + g * 4 + r;
                float v = acc[kt][dt][r];
                if (ns == 0) v -= sA[b * KK + k] * codes[k * DD + d];
                atomicAdd(&out[((size_t)b * KK + k) * DD + d], v);
            }
        }
    }
}

extern "C" void kernel_launch(void* const* d_in, const int* in_sizes, int n_in,
                              void* d_out, int out_size, void* d_ws, size_t ws_size,
                              hipStream_t stream) {
    const float* x = (const float*)d_in[0];
    const float* codes = (const float*)d_in[1];
    const float* scale = (const float*)d_in[2];
    float* out = (float*)d_out;
    float* ws = (float*)d_ws;

    float* sA   = ws;            // 512 floats
    float* c2w  = ws + 512;      // 32
    float* s2w  = ws + 544;      // 32
    float* Abuf = ws + 576;      // B*N*K = 2,097,152 floats (~8.4 MB)

    hipMemsetAsync(d_out, 0, (size_t)out_size * sizeof(float), stream);
    k_prep<<<1, 256, 0, stream>>>(codes, scale, sA, c2w, s2w);
    k_assign<<<512, 256, 0, stream>>>(x, codes, c2w, s2w, Abuf, sA);
    k_agg<<<256, 512, 0, stream>>>(x, codes, Abuf, sA, out);
}

// Round 2
// 74.948 us; speedup vs baseline: 1.0131x; 1.0131x over previous
//
#include <hip/hip_runtime.h>
#include <hip/hip_bf16.h>

#define KK 32
#define DD 512
#define BB 16
#define NN 4096

typedef __attribute__((ext_vector_type(8))) short short8;
typedef __attribute__((ext_vector_type(4))) float f32x4;

__device__ __forceinline__ unsigned short f2bf(float f) {
    unsigned u = __builtin_bit_cast(unsigned, f);
    u += 0x7fffu + ((u >> 16) & 1u);   // round-to-nearest-even bf16
    return (unsigned short)(u >> 16);
}

// ---------------- kernel 0: zero out, c2[k], s2[k], zero sA ----------------
// grid 256 x 256: every block zeros a slice of out; block 0 also does c2/s2/sA
__global__ __launch_bounds__(256) void k_prep(const float* __restrict__ codes,
                                              const float* __restrict__ scale,
                                              float* __restrict__ sA,
                                              float* __restrict__ c2w,
                                              float* __restrict__ s2w,
                                              float* __restrict__ out) {
    int tid = threadIdx.x;
    float4 z = {0.f, 0.f, 0.f, 0.f};
    reinterpret_cast<float4*>(out)[blockIdx.x * 256 + tid] = z;   // 256*256*4 = 262144 floats
    if (blockIdx.x != 0) return;

    __shared__ float red[KK][8];
    int k = tid >> 3, part = tid & 7;
    const float4* p = reinterpret_cast<const float4*>(codes + k * DD + part * 64);
    float s = 0.f;
#pragma unroll
    for (int i = 0; i < 16; ++i) {
        float4 v = p[i];
        s += v.x * v.x + v.y * v.y + v.z * v.z + v.w * v.w;
    }
    red[k][part] = s;
    sA[tid] = 0.f;
    sA[tid + 256] = 0.f;
    __syncthreads();
    if (tid < KK) {
        float c2 = 0.f;
#pragma unroll
        for (int j = 0; j < 8; ++j) c2 += red[tid][j];
        c2w[tid] = c2;
        float sc = scale[tid];
        s2w[tid] = sc * sc;
    }
}

// ---------------- kernel 1: softmax assignments A (bf16, packed) ----------------
// block = 256 threads (4 waves), 128 tokens/block, grid = 16*32 = 512
// x staged through LDS: coalesced float4 global reads, swizzled [d][tok] bf16 tiles
__global__ __launch_bounds__(256) void k_assign(const float* __restrict__ x,
                                                const float* __restrict__ codes,
                                                const float* __restrict__ c2w,
                                                const float* __restrict__ s2w,
                                                unsigned short* __restrict__ Aout,
                                                float* __restrict__ sA) {
    __shared__ unsigned short codes_lds[KK][DD + 8];     // 33280 B
    __shared__ unsigned short xt[2][32 * 128];           // 2 x 8 KB, swizzled [d][tok]
    __shared__ float x2_lds[8][128];
    __shared__ float x2f[128];

    int tid = threadIdx.x;
    int bid = blockIdx.x;
    int b = bid >> 5;
    int tok_base = (bid & 31) << 7;

    // stage codes -> LDS bf16
#pragma unroll
    for (int i = 0; i < 16; ++i) {
        int idx = i * 1024 + tid * 4;
        int k = idx >> 9, d = idx & 511;
        float4 v = *reinterpret_cast<const float4*>(codes + idx);
        ushort4 h;
        h.x = f2bf(v.x); h.y = f2bf(v.y); h.z = f2bf(v.z); h.w = f2bf(v.w);
        *reinterpret_cast<ushort4*>(&codes_lds[k][d]) = h;
    }

    int lane = tid & 63;
    int w = tid >> 6;          // wave -> 32 tokens
    int g = lane >> 4, c = lane & 15;
    int t0 = w * 32;

    // staging assignment: thread covers tokens 4*scol..+3 at rows srow+8i
    int srow = tid >> 5;       // 0..7
    int scol = tid & 31;       // float4 column
    const float* xbase = x + (size_t)b * DD * NN + tok_base + scol * 4;

    float s2k[2], c2k[2];
#pragma unroll
    for (int kt = 0; kt < 2; ++kt) {
        s2k[kt] = s2w[c + 16 * kt];
        c2k[kt] = c2w[c + 16 * kt];
    }

    f32x4 acc[2][2] = {};
    float x2p[4] = {0.f, 0.f, 0.f, 0.f};
    float4 ld[4];

    // load tile 0
#pragma unroll
    for (int i = 0; i < 4; ++i)
        ld[i] = *reinterpret_cast<const float4*>(xbase + (size_t)(srow + 8 * i) * NN);

    // write tile (+ exact fp32 x2 accumulation)
    auto write_tile = [&](int buf) {
        char* bp = reinterpret_cast<char*>(&xt[buf][0]);
#pragma unroll
        for (int i = 0; i < 4; ++i) {
            int row = srow + 8 * i;
            x2p[0] += ld[i].x * ld[i].x;
            x2p[1] += ld[i].y * ld[i].y;
            x2p[2] += ld[i].z * ld[i].z;
            x2p[3] += ld[i].w * ld[i].w;
            ushort4 h;
            h.x = f2bf(ld[i].x); h.y = f2bf(ld[i].y);
            h.z = f2bf(ld[i].z); h.w = f2bf(ld[i].w);
            int byte = row * 256 + scol * 8;
            byte ^= ((row >> 3) & 3) << 5;
            *reinterpret_cast<ushort4*>(bp + byte) = h;
        }
    };

    write_tile(0);
    __syncthreads();

    for (int it = 0; it < 16; ++it) {
        int cur = it & 1;
        if (it < 15) {
#pragma unroll
            for (int i = 0; i < 4; ++i)
                ld[i] = *reinterpret_cast<const float4*>(
                    xbase + (size_t)((it + 1) * 32 + srow + 8 * i) * NN);
        }
        // A-frags from swizzled LDS tile
        const char* bp = reinterpret_cast<const char*>(&xt[cur][0]);
        short8 af[2];
#pragma unroll
        for (int tt = 0; tt < 2; ++tt) {
#pragma unroll
            for (int j = 0; j < 8; ++j) {
                int dl = g * 8 + j;
                int byte = dl * 256 + (t0 + tt * 16 + c) * 2;
                byte ^= ((dl >> 3) & 3) << 5;
                af[tt][j] = *reinterpret_cast<const short*>(bp + byte);
            }
        }
        int d0 = it * 32;
        short8 bf0 = *reinterpret_cast<const short8*>(&codes_lds[c][d0 + g * 8]);
        short8 bf1 = *reinterpret_cast<const short8*>(&codes_lds[c + 16][d0 + g * 8]);
        acc[0][0] = __builtin_amdgcn_mfma_f32_16x16x32_bf16(af[0], bf0, acc[0][0], 0, 0, 0);
        acc[0][1] = __builtin_amdgcn_mfma_f32_16x16x32_bf16(af[0], bf1, acc[0][1], 0, 0, 0);
        acc[1][0] = __builtin_amdgcn_mfma_f32_16x16x32_bf16(af[1], bf0, acc[1][0], 0, 0, 0);
        acc[1][1] = __builtin_amdgcn_mfma_f32_16x16x32_bf16(af[1], bf1, acc[1][1], 0, 0, 0);
        if (it < 15) write_tile(cur ^ 1);
        __syncthreads();
    }

    // reduce x2 partials (exact fp32 over raw x)
#pragma unroll
    for (int q = 0; q < 4; ++q) x2_lds[srow][scol * 4 + q] = x2p[q];
    __syncthreads();
    if (tid < 128) {
        float s = 0.f;
#pragma unroll
        for (int j = 0; j < 8; ++j) s += x2_lds[j][tid];
        x2f[tid] = s;
    }
    __syncthreads();

    unsigned short* Ab = Aout + (size_t)b * NN * KK;
    float pA0 = 0.f, pA1 = 0.f;
#pragma unroll
    for (int tt = 0; tt < 2; ++tt) {
#pragma unroll
        for (int r = 0; r < 4; ++r) {
            int tloc = t0 + tt * 16 + g * 4 + r;
            float x2r = x2f[tloc];
            float d0v = s2k[0] * (x2r - 2.f * acc[tt][0][r] + c2k[0]);
            float d1v = s2k[1] * (x2r - 2.f * acc[tt][1][r] + c2k[1]);
            float m = fmaxf(d0v, d1v);
            m = fmaxf(m, __shfl_xor(m, 1));
            m = fmaxf(m, __shfl_xor(m, 2));
            m = fmaxf(m, __shfl_xor(m, 4));
            m = fmaxf(m, __shfl_xor(m, 8));
            float p0 = __expf(d0v - m), p1 = __expf(d1v - m);
            float s = p0 + p1;
            s += __shfl_xor(s, 1);
            s += __shfl_xor(s, 2);
            s += __shfl_xor(s, 4);
            s += __shfl_xor(s, 8);
            float inv = 1.0f / s;
            float a0 = p0 * inv, a1 = p1 * inv;
            // packed bf16 layout: [n/8][k=32][n%8]
            int n = tok_base + tloc;
            unsigned short* pa = Ab + ((size_t)(n >> 3) << 8) + (n & 7);
            pa[c * 8] = f2bf(a0);
            pa[(c + 16) * 8] = f2bf(a1);
            pA0 += a0;
            pA1 += a1;
        }
    }
    pA0 += __shfl_xor(pA0, 16); pA0 += __shfl_xor(pA0, 32);
    pA1 += __shfl_xor(pA1, 16); pA1 += __shfl_xor(pA1, 32);
    if (g == 0) {
        atomicAdd(&sA[b * KK + c], pA0);
        atomicAdd(&sA[b * KK + c + 16], pA1);
    }
}

// ---------------- kernel 2: e[b,k,d] = sum_n a[n,k] x[d,n] - sA[b,k]*codes[k,d] ----------------
// block = 512 threads (8 waves), wave owns 64 d-cols, grid = 16 b * 16 n-chunks = 256
__global__ __launch_bounds__(512) void k_agg(const float* __restrict__ x,
                                             const float* __restrict__ codes,
                                             const unsigned short* __restrict__ Ain,
                                             const float* __restrict__ sA,
                                             float* __restrict__ out) {
    int tid = threadIdx.x;
    int lane = tid & 63;
    int w = tid >> 6;
    int g = lane >> 4, c = lane & 15;
    int bid = blockIdx.x;
    int b = bid >> 4;
    int ns = bid & 15;
    int nb = ns << 8;

    f32x4 acc[2][4] = {};
    const float* xb = x + (size_t)b * DD * NN;
    const unsigned short* Ab = Ain + (size_t)b * NN * KK;

    for (int nn = 0; nn < 256; nn += 32) {
        int n0 = nb + nn + g * 8;                 // multiple of 8
        const unsigned short* pa = Ab + ((size_t)(n0 >> 3) << 8);
        short8 af[2];
        af[0] = *reinterpret_cast<const short8*>(pa + c * 8);          // k = c
        af[1] = *reinterpret_cast<const short8*>(pa + c * 8 + 128);    // k = c+16
        short8 bfrag[4];
#pragma unroll
        for (int dt = 0; dt < 4; ++dt) {
            const float* px = xb + (size_t)(w * 64 + dt * 16 + c) * NN + n0;
            float4 v0 = *reinterpret_cast<const float4*>(px);
            float4 v1 = *reinterpret_cast<const float4*>(px + 4);
            short8 t;
            t[0] = (short)f2bf(v0.x); t[1] = (short)f2bf(v0.y);
            t[2] = (short)f2bf(v0.z); t[3] = (short)f2bf(v0.w);
            t[4] = (short)f2bf(v1.x); t[5] = (short)f2bf(v1.y);
            t[6] = (short)f2bf(v1.z); t[7] = (short)f2bf(v1.w);
            bfrag[dt] = t;
        }
#pragma unroll
        for (int kt = 0; kt < 2; ++kt)
#pragma unroll
            for (int dt = 0; dt < 4; ++dt)
                acc[kt][dt] = __builtin_amdgcn_mfma_f32_16x16x32_bf16(af[kt], bfrag[dt],
                                                                      acc[kt][dt], 0, 0, 0);
    }

#pragma unroll
    for (int kt = 0; kt < 2; ++kt) {
#pragma unroll
        for (int dt = 0; dt < 4; ++dt) {
            int d = w * 64 + dt * 16 + c;
#pragma unroll
            for (int r = 0; r < 4; ++r) {
                int k = kt * 16 + g * 4 + r;
                float v = acc[kt][dt][r];
                if (ns == 0) v -= sA[b * KK + k] * codes[k * DD + d];
                atomicAdd(&out[((size_t)b * KK + k) * DD + d], v);
            }
        }
    }
}

extern "C" void kernel_launch(void* const* d_in, const int* in_sizes, int n_in,
                              void* d_out, int out_size, void* d_ws, size_t ws_size,
                              hipStream_t stream) {
    const float* x = (const float*)d_in[0];
    const float* codes = (const float*)d_in[1];
    const float* scale = (const float*)d_in[2];
    float* out = (float*)d_out;
    float* ws = (float*)d_ws;

    float* sA = ws;                                    // 512 floats
    float* c2w = ws + 512;                             // 32
    float* s2w = ws + 544;                             // 32
    unsigned short* Abuf = (unsigned short*)(ws + 576); // B*N*K bf16 (~4.2 MB), 16B-aligned

    k_prep<<<256, 256, 0, stream>>>(codes, scale, sA, c2w, s2w, out);
    k_assign<<<512, 256, 0, stream>>>(x, codes, c2w, s2w, Abuf, sA);
    k_agg<<<256, 512, 0, stream>>>(x, codes, Abuf, sA, out);
}